// Round 3
// baseline (182.146 us; speedup 1.0000x reference)
//
#include <hip/hip_runtime.h>

// Problem constants (fixed by the reference):
//   VOCAB=50000, N_NUM=5000, D=128, B=512, L=512
// Inputs (d_in order — all float tensors fp32, ints int32):
//   0 feature_ids            int32  [262144]
//   1 feature_values         fp32   [262144]
//   2 cat_table              fp32   [45001, 128]   (row 0 = all zeros, padding)
//   3 num_weight             fp32   [5000, 128]
//   4 num_bias               fp32   [5000, 128]
// Output: fp32 [262144, 128]
//
// Structure: one wave owns 16 consecutive positions (16 rows x 128 fp32 =
// 8 float4-segments per lane). Routes broadcast via __shfl; no LDS tiles.
//
// R3 change: L3-warm prologue. The harness poisons 646 MB between
// iterations, evicting the gather tables from L2/L3 — so the kernel's
// random 512B row gathers are cold HBM reads interleaved with the 134 MB
// NT write stream (read/write turnaround => ~2.3 TB/s effective, kernel
// ~75 us vs ~27 us traffic floor).  Each block now streams a coalesced
// slice of all three tables first (28 MB total, ~5 us device-wide, pure
// read stream at full BW) to repopulate the die-level Infinity Cache.
// Gathers then hit L3 and HBM sees a nearly pure write stream.
// R1's exec-masked bias-load skip + 32-bit row offsets kept (neutral but
// strictly-less traffic).

constexpr int D  = 128;
constexpr int BL = 512 * 512;
constexpr int POS_PER_WAVE  = 16;
constexpr int WAVES_PER_BLK = 4;   // 256 threads
constexpr int POS_PER_BLK   = POS_PER_WAVE * WAVES_PER_BLK;  // 64
constexpr int NBLOCKS       = BL / POS_PER_BLK;              // 4096
constexpr int NTHREADS      = NBLOCKS * 256;                 // 1048576

// float4 element counts of the three tables
constexpr int CAT_F4 = 45001 * (D / 4);   // 1,440,032
constexpr int NUM_F4 = 5000  * (D / 4);   //   160,000

typedef float vfloat4 __attribute__((ext_vector_type(4)));
union F4 { float4 h; vfloat4 n; };

__global__ __launch_bounds__(256) void emb_kernel(
    const int*    __restrict__ feature_ids,
    const float*  __restrict__ feature_values,
    const float*  __restrict__ cat_table,
    const float*  __restrict__ num_weight,
    const float*  __restrict__ num_bias,
    float*        __restrict__ out)
{
    const int tid  = threadIdx.x;
    const int lane = tid & 63;
    const int wave = tid >> 6;
    const int gtid = blockIdx.x * 256 + tid;          // 0 .. 1048575

    // ---- Phase 0: L3 warm — sequential coalesced sweep of all tables ---
    // Pure-read stream repopulates the Infinity Cache after the harness
    // poison evicted it.  Loads kept live via empty asm (no DCE), no
    // stores.  ~28 MB device-wide ≈ 5 us.
    {
        float acc = 0.0f;
        const float4* ct = (const float4*)cat_table;
        float4 w0 = ct[gtid];                          // gtid < 1,048,576 < CAT_F4
        acc += w0.x + w0.w;
        const int j = gtid + NTHREADS;
        if (j < CAT_F4) {                              // 391,456 threads
            float4 w1 = ct[j];
            acc += w1.x + w1.w;
        }
        if (gtid < NUM_F4) {
            float4 w2 = ((const float4*)num_weight)[gtid];
            float4 w3 = ((const float4*)num_bias)[gtid];
            acc += w2.x + w2.w + w3.x + w3.w;
        }
        asm volatile("" :: "v"(acc));                  // keep loads live
    }

    const int wbase = blockIdx.x * POS_PER_BLK + wave * POS_PER_WAVE;

    // Wave-local routing: one coalesced load of the wave's 16 ids/values
    // (lanes 16.. replicate — same cache lines, broadcast in the TA).
    const int  myp = lane & 15;
    const int  id  = feature_ids[wbase + myp];
    const float mv = feature_values[wbase + myp];
    // route < 0  -> numerical, row = -route-1
    // route >= 0 -> categorical row (0 for padding id 0)
    const int route = (id >= 1 && id <= 5000) ? -id
                    : ((id > 5000) ? id - 5000 : 0);

    const int sub  = (lane & 31) * 4;   // float offset within the 128-wide row
    const int half = lane >> 5;         // which of the 2 positions per k-iter

    // ---- Phase 1: issue all 8 A-row loads (always needed) --------------
    float4 av[8];
    float  sc[8];
    int    brow[8];                     // bias row if numerical, else -1
#pragma unroll
    for (int k = 0; k < 8; ++k) {
        const int   p  = k * 2 + half;          // position within wave [0,16)
        const int   rt = __shfl(route, p);
        const float vv = __shfl(mv, p);
        const bool isnum = rt < 0;
        const int  row   = isnum ? (-rt - 1) : rt;     // 32-bit, fits easily
        const float* a   = (isnum ? num_weight : cat_table) + row * D + sub;
        av[k]   = *(const float4*)a;
        sc[k]   = isnum ? vv : 1.0f;
        brow[k] = isnum ? row : -1;
    }

    // ---- Phase 2: B-row loads only where numerical ----------------------
    // isnum is uniform per 32-lane half => exec-masked branch; fully
    // skipped (s_cbranch_execz) when both halves are categorical (~81%).
    float4 bv[8];
#pragma unroll
    for (int k = 0; k < 8; ++k) {
        bv[k] = make_float4(0.f, 0.f, 0.f, 0.f);
        if (brow[k] >= 0)
            bv[k] = *(const float4*)(num_bias + brow[k] * D + sub);
    }

    // ---- Phase 3: fma + non-temporal streaming store --------------------
    // (write-once output must not evict the gather tables from L2/L3)
    float* const obase = out + (long long)wbase * D;
#pragma unroll
    for (int k = 0; k < 8; ++k) {
        F4 r;
        r.h.x = fmaf(av[k].x, sc[k], bv[k].x);
        r.h.y = fmaf(av[k].y, sc[k], bv[k].y);
        r.h.z = fmaf(av[k].z, sc[k], bv[k].z);
        r.h.w = fmaf(av[k].w, sc[k], bv[k].w);
        // segment index within wave region: k*64 + lane (contiguous 1 KB/iter)
        vfloat4* dst = (vfloat4*)(obase + (k * 64 + lane) * 4);
        __builtin_nontemporal_store(r.n, dst);
    }
}

extern "C" void kernel_launch(void* const* d_in, const int* in_sizes, int n_in,
                              void* d_out, int out_size, void* d_ws, size_t ws_size,
                              hipStream_t stream) {
    const int*   feature_ids    = (const int*)  d_in[0];
    const float* feature_values = (const float*)d_in[1];
    const float* cat_table      = (const float*)d_in[2];
    const float* num_weight     = (const float*)d_in[3];
    const float* num_bias       = (const float*)d_in[4];
    float*       out            = (float*)      d_out;

    emb_kernel<<<NBLOCKS, 256, 0, stream>>>(
        feature_ids, feature_values, cat_table, num_weight, num_bias, out);
}

// Round 4
// 179.177 us; speedup vs baseline: 1.0166x; 1.0166x over previous
//
#include <hip/hip_runtime.h>

// Problem constants (fixed by the reference):
//   VOCAB=50000, N_NUM=5000, D=128, B=512, L=512
// Inputs (d_in order — all float tensors fp32, ints int32):
//   0 feature_ids            int32  [262144]
//   1 feature_values         fp32   [262144]
//   2 cat_table              fp32   [45001, 128]   (row 0 = all zeros, padding)
//   3 num_weight             fp32   [5000, 128]
//   4 num_bias               fp32   [5000, 128]
// Output: fp32 [262144, 128]
//
// Structure: one wave owns 16 consecutive positions (16 rows x 128 fp32 =
// 8 float4-segments per lane). All lanes coalesce-load the 16 ids/values
// once; routes broadcast via __shfl (no LDS, no syncthreads).
//
// R4 change (single variable vs R2): non-temporal stores -> PLAIN stores.
// Evidence trail: R1 (−45% read VMEM) null, R3 (L3 table warm) null — the
// reads are L3-resident and issue-count doesn't matter.  The one path
// never varied is the 134 MB output stream: NT stores give the kernel an
// effective ~1.8 TB/s write rate while the harness's plain-store fill
// hits 6.6-6.8 TB/s in the same graph.  NT's original purpose (protect
// L2 table residency) is moot per R3.  Full-line coalesced dwordx4
// stores through L2 write-combine at stream rate.

constexpr int D  = 128;
constexpr int BL = 512 * 512;
constexpr int POS_PER_WAVE  = 16;
constexpr int WAVES_PER_BLK = 4;   // 256 threads
constexpr int POS_PER_BLK   = POS_PER_WAVE * WAVES_PER_BLK;  // 64

__global__ __launch_bounds__(256) void emb_kernel(
    const int*    __restrict__ feature_ids,
    const float*  __restrict__ feature_values,
    const float*  __restrict__ cat_table,
    const float*  __restrict__ num_weight,
    const float*  __restrict__ num_bias,
    float*        __restrict__ out)
{
    const int tid  = threadIdx.x;
    const int lane = tid & 63;
    const int wave = tid >> 6;
    const int wbase = blockIdx.x * POS_PER_BLK + wave * POS_PER_WAVE;  // first position

    // Wave-local routing: one coalesced load of the wave's 16 ids/values
    // (lanes 16.. replicate — same cache lines, broadcast in the TA).
    const int  myp = lane & 15;
    const int  id  = feature_ids[wbase + myp];
    const float mv = feature_values[wbase + myp];
    // route < 0  -> numerical, row = -route-1
    // route >= 0 -> categorical row (0 for padding id 0)
    const int route = (id >= 1 && id <= 5000) ? -id
                    : ((id > 5000) ? id - 5000 : 0);

    const int sub  = (lane & 31) * 4;   // float offset within the 128-wide row
    const int half = lane >> 5;         // which of the 2 positions per k-iter

    // ---- Phase 1: issue all 8 A-row loads (always needed) --------------
    float4 av[8];
    float  sc[8];
    int    brow[8];                     // bias row if numerical, else -1
#pragma unroll
    for (int k = 0; k < 8; ++k) {
        const int   p  = k * 2 + half;          // position within wave [0,16)
        const int   rt = __shfl(route, p);
        const float vv = __shfl(mv, p);
        const bool isnum = rt < 0;
        const int  row   = isnum ? (-rt - 1) : rt;     // 32-bit, fits easily
        const float* a   = (isnum ? num_weight : cat_table) + row * D + sub;
        av[k]   = *(const float4*)a;
        sc[k]   = isnum ? vv : 1.0f;
        brow[k] = isnum ? row : -1;
    }

    // ---- Phase 2: B-row loads only where numerical ----------------------
    // isnum is uniform per 32-lane half => exec-masked branch; fully
    // skipped (s_cbranch_execz) when both halves are categorical (~81%).
    float4 bv[8];
#pragma unroll
    for (int k = 0; k < 8; ++k) {
        bv[k] = make_float4(0.f, 0.f, 0.f, 0.f);
        if (brow[k] >= 0)
            bv[k] = *(const float4*)(num_bias + brow[k] * D + sub);
    }

    // ---- Phase 3: fma + PLAIN coalesced store ---------------------------
    // categorical: fma(av, 1.0, 0) == av ; numerical: av*v + bias.
    float* const obase = out + (long long)wbase * D;
#pragma unroll
    for (int k = 0; k < 8; ++k) {
        float4 r;
        r.x = fmaf(av[k].x, sc[k], bv[k].x);
        r.y = fmaf(av[k].y, sc[k], bv[k].y);
        r.z = fmaf(av[k].z, sc[k], bv[k].z);
        r.w = fmaf(av[k].w, sc[k], bv[k].w);
        // segment index within wave region: k*64 + lane (contiguous 1 KB/iter)
        *(float4*)(obase + (k * 64 + lane) * 4) = r;
    }
}

extern "C" void kernel_launch(void* const* d_in, const int* in_sizes, int n_in,
                              void* d_out, int out_size, void* d_ws, size_t ws_size,
                              hipStream_t stream) {
    const int*   feature_ids    = (const int*)  d_in[0];
    const float* feature_values = (const float*)d_in[1];
    const float* cat_table      = (const float*)d_in[2];
    const float* num_weight     = (const float*)d_in[3];
    const float* num_bias       = (const float*)d_in[4];
    float*       out            = (float*)      d_out;

    const int blocks = BL / POS_PER_BLK;   // 4096, exact
    emb_kernel<<<blocks, 256, 0, stream>>>(
        feature_ids, feature_values, cat_table, num_weight, num_bias, out);
}